// Round 9
// baseline (484.620 us; speedup 1.0000x reference)
//
#include <hip/hip_runtime.h>

#define TT 128
#define BB 32
#define II 128
#define HH 320
#define OO 32
#define GG 8
#define HPAD 129   // s_hist row pitch (pad: rows are read down-column in final rewrite)

static __device__ __forceinline__ float fexp2(float x) { return __builtin_amdgcn_exp2f(x); }
static __device__ __forceinline__ float frcp(float x)  { return __builtin_amdgcn_rcpf(x); }

// tanh for x >= 0: 1 - 2/(e^{2x}+1), e^{2x} = exp2(x * 2*log2(e))
static __device__ __forceinline__ float tanh_pos(float x) {
    float e = fexp2(x * 2.8853900817779268f);
    return 1.0f - 2.0f * frcp(e + 1.0f);
}

// ---- DPP wave-64 sum reduce (VALU pipe) ----
template<int CTRL>
static __device__ __forceinline__ float dpp_add(float v) {
    int t = __builtin_amdgcn_update_dpp(0, __builtin_bit_cast(int, v),
                                        CTRL, 0xf, 0xf, true);
    return v + __builtin_bit_cast(float, t);
}
static __device__ __forceinline__ float bcast63(float v) {
    return __builtin_bit_cast(float,
        __builtin_amdgcn_readlane(__builtin_bit_cast(int, v), 63));
}

__global__ __launch_bounds__(512, 1)
void leaky_rnn_kernel(const float* __restrict__ x, const float* __restrict__ Rs,
                      const float* __restrict__ Wx2h, const float* __restrict__ Wh2h,
                      const float* __restrict__ bh2h, const float* __restrict__ Wh2o,
                      const float* __restrict__ bh2o, const float* __restrict__ Wattn,
                      const float* __restrict__ battn, const float* __restrict__ cplas,
                      float* __restrict__ out, float* __restrict__ hs,
                      unsigned* __restrict__ ctr)
{
    const int tid  = threadIdx.x;
    const int bid  = blockIdx.x;
    const int b    = bid >> 3;     // batch  (round-0 proven mapping)
    const int sub  = bid & 7;      // 8 blocks per batch, 40 rows each
    const int w    = tid >> 6;     // wave 0..7
    const int lane = tid & 63;
    const int h0   = sub * 40;

    __shared__ float s_out[2][HH];       // double-buffered prev-output (by t parity)
    __shared__ float s_hist[40 * HPAD];  // own 40 rows x 128 t (true values); in-loop
                                         // WRITTEN only, READ only in final phase.
    __shared__ float s_hs[16 * HH];      // readout staging

    // ---- one-time init ----
    if (tid < HH) { s_out[0][tid] = 0.f; s_out[1][tid] = 0.f; }  // output0 = relu(0)

    // attention weights fully in registers: this lane's 5 column-slices of all
    // 8 groups (replaces s_ea + B1: every wave computes all logits redundantly,
    // bit-identically -> one barrier per step).
    float ea_r[8][5], ba[8];
#pragma unroll
    for (int g = 0; g < 8; ++g) {
        ba[g] = battn[g];
#pragma unroll
        for (int k = 0; k < 5; ++k) {
            int j = lane + 64 * k;
            float m = (j < 256) ? 1.f : (j == 256 ? -1.f : 0.f);  // mask_a (zc=63!)
            ea_r[g][k] = fmaxf(Wattn[g * HH + j], 0.f) * m;
        }
    }

    // plastic weights in registers: 5 rows/wave, lane owns cols {lane, lane+64,...}
    float wx[5][2], wh[5][5], st[5], bh[5];
    int hrow[5];
#pragma unroll
    for (int r = 0; r < 5; ++r) {
        int h = h0 + w * 5 + r;
        hrow[r] = h;
        bh[r] = bh2h[h];
        st[r] = 0.f;
#pragma unroll
        for (int c = 0; c < 2; ++c)
            wx[r][c] = fmaxf(Wx2h[h * II + lane + 64 * c], 0.f);   // wx0 = relu(W_x2h)
#pragma unroll
        for (int c = 0; c < 5; ++c) {
            int j = lane + 64 * c;
            float v = fmaxf(Wh2h[h * HH + j], 0.f);
            v = (c == 4) ? -v : v;            // sign_h: j>=256 -> -1
            wh[r][c] = (j == h) ? 0.f : v;    // zero diagonal (1-eye)
        }
    }
    float c0 = fabsf(cplas[0]), c1 = fabsf(cplas[1]), c2 = fabsf(cplas[2]);
    float c3 = fabsf(cplas[3]), c4 = fabsf(cplas[4]), c5 = fabsf(cplas[5]);

    const float AX  = (float)(0.02 / 0.1);   // 0.2
    const float AW  = (float)(0.02 / 0.2);   // 0.1
    const float OMX = 1.f - AX;
    const float OMW = 1.f - AW;
    const float L2E = 1.4426950408889634f;

    // prefetch x (both halves, per-thread regs) and Rs for t=0
    float xv0n = x[b * II + lane];
    float xv1n = x[b * II + lane + 64];
    float Rvn  = Rs[b];

    // pre-warm t=0 publish lines (LLC/MALL allocation off the critical path)
    if (lane < 5)
        __hip_atomic_store(&hs[b * HH + h0 + w * 5 + lane], 0.0f,
                           __ATOMIC_RELAXED, __HIP_MEMORY_SCOPE_AGENT);

    __syncthreads();

#pragma unroll 1
    for (int t = 0; t < TT; ++t) {
        const float* so_cur = s_out[t & 1];
        float*       so_nxt = s_out[(t + 1) & 1];
        float xv0 = xv0n, xv1 = xv1n;
        float A   = AW * Rvn;

        // ---- this lane's 5 hidden-state values (used by logits AND dots) ----
        float oc[5];
#pragma unroll
        for (int c = 0; c < 5; ++c) oc[c] = so_cur[lane + 64 * c];

        // ---- all 8 attention logits, redundantly per wave (8-way ILP DPP;
        //      bit-identical chain + reduction order to the staged version) ----
        float lg[8];
#pragma unroll
        for (int g = 0; g < 8; ++g) {
            float lp = 0.f;
#pragma unroll
            for (int k = 0; k < 5; ++k) lp = fmaf(ea_r[g][k], oc[k], lp);
            lg[g] = lp;
        }
#define DPP_L8(CTRL) { \
        lg[0]=dpp_add<CTRL>(lg[0]); lg[1]=dpp_add<CTRL>(lg[1]); \
        lg[2]=dpp_add<CTRL>(lg[2]); lg[3]=dpp_add<CTRL>(lg[3]); \
        lg[4]=dpp_add<CTRL>(lg[4]); lg[5]=dpp_add<CTRL>(lg[5]); \
        lg[6]=dpp_add<CTRL>(lg[6]); lg[7]=dpp_add<CTRL>(lg[7]); }
        DPP_L8(0x111) DPP_L8(0x112) DPP_L8(0x114)
        DPP_L8(0x118) DPP_L8(0x142) DPP_L8(0x143)
#undef DPP_L8
#pragma unroll
        for (int g = 0; g < 8; ++g) lg[g] = bcast63(lg[g]) + ba[g];

        // ---- softmax (identical op order) ----
        float mx = lg[0];
#pragma unroll
        for (int g = 1; g < 8; ++g) mx = fmaxf(mx, lg[g]);
        float se = 0.f, eg[8];
#pragma unroll
        for (int g = 0; g < 8; ++g) { eg[g] = fexp2((lg[g] - mx) * L2E); se += eg[g]; }
        float rinv = frcp(se);
        float xmc0 = xv0 * eg[lane >> 4] * 8.f * rinv;
        float xmc1 = xv1 * eg[(lane >> 4) + 4] * 8.f * rinv;

        // ---- 5 row-dot partials, 5-way ILP DPP reduce ----
        float p[5];
#pragma unroll
        for (int r = 0; r < 5; ++r) {
            int h = hrow[r];
            float pp = fmaxf(wx[r][0], 0.f) * xmc0;
            pp = fmaf(fmaxf(wx[r][1], 0.f), xmc1, pp);
#pragma unroll
            for (int c = 0; c < 5; ++c) {
                float wv = fmaxf(wh[r][c], 0.f);
                float so = (c == 4) ? -oc[4] : oc[c];        // sign_h fold
                float term = wv * so;
                term = ((lane + 64 * c) == h) ? 0.f : term;  // exclude diagonal
                pp += term;
            }
            p[r] = pp;
        }
#define DPP_L5(CTRL) { \
        p[0]=dpp_add<CTRL>(p[0]); p[1]=dpp_add<CTRL>(p[1]); \
        p[2]=dpp_add<CTRL>(p[2]); p[3]=dpp_add<CTRL>(p[3]); \
        p[4]=dpp_add<CTRL>(p[4]); }
        DPP_L5(0x111) DPP_L5(0x112) DPP_L5(0x114)
        DPP_L5(0x118) DPP_L5(0x142) DPP_L5(0x143)
#undef DPP_L5

        float no[5];
#pragma unroll
        for (int r = 0; r < 5; ++r) {
            float total = bcast63(p[r]) + bh[r];
            st[r] = fmaf(st[r], OMX, total * AX);
            no[r] = tanh_pos(fmaxf(st[r], 0.f));
        }

        // ---- batched publish (lanes 0..4, one line). Biased +2: poison /
        //      memset-0 / pre-warm-0 all < 1. Publisher also writes its true
        //      value to so_nxt (LDS fast path, ordered by B2 -- the fix that
        //      round-6's s_hist fast path lacked). Then ROLLING PRE-WARM:
        //      store 0.0f to the SAME THREAD's t+1 slot -- per-location
        //      program order keeps the real t+1 value authoritative; the line
        //      becomes MALL-resident a full period early, so the t+1 publish
        //      merges without an HBM fetch. ----
        {
            float pub = no[0];
            pub = (lane == 1) ? no[1] : pub;
            pub = (lane == 2) ? no[2] : pub;
            pub = (lane == 3) ? no[3] : pub;
            pub = (lane == 4) ? no[4] : pub;
            if (lane < 5) {
                __hip_atomic_store(&hs[(t * BB + b) * HH + h0 + w * 5 + lane], pub + 2.0f,
                                   __ATOMIC_RELAXED, __HIP_MEMORY_SCOPE_AGENT);
                s_hist[(w * 5 + lane) * HPAD + t] = pub;   // true value for final rewrite
                so_nxt[h0 + w * 5 + lane] = pub;           // own-row fast path (B2-ordered)
                if (t + 1 < TT)
                    __hip_atomic_store(&hs[((t + 1) * BB + b) * HH + h0 + w * 5 + lane],
                                       0.0f, __ATOMIC_RELAXED, __HIP_MEMORY_SCOPE_AGENT);
            }
        }

        // ---- plastic weight update (regs only; overlaps store propagation) ----
        if (t < TT - 1) {
            float Ac0 = A * c0, Ac1 = A * c1, Ac2 = A * c2;
            float Ac3 = A * c3, Ac4 = A * c4, Ac5 = A * c5;
#pragma unroll
            for (int r = 0; r < 5; ++r) {
                float u  = fmaf(Ac2, no[r], Ac0);
                float v  = Ac1 * no[r];
                float pp = fmaf(Ac5, no[r], Ac3);
                float qq = Ac4 * no[r];
                wx[r][0] = fmaf(wx[r][0], OMW, fmaf(u, xmc0, v));
                wx[r][1] = fmaf(wx[r][1], OMW, fmaf(u, xmc1, v));
#pragma unroll
                for (int c = 0; c < 5; ++c)
                    wh[r][c] = fmaf(wh[r][c], OMW, fmaf(pp, oc[c], qq));
            }
        }

        // prefetch next x/R while publish stores are in flight
        if (t + 1 < TT) {
            xv0n = x[((t + 1) * BB + b) * II + lane];
            xv1n = x[((t + 1) * BB + b) * II + lane + 64];
            Rvn  = Rs[(t + 1) * BB + b];
        }

        // ---- gather the 280 REMOTE rows into the other buffer (own 40 rows
        //      written via so_nxt above; B2 orders). 4-deep pipelined poll. ----
        if (t < TT - 1 && tid < HH && !(tid >= h0 && tid < h0 + 40)) {
            const float* p2 = &hs[(t * BB + b) * HH + tid];
            float va = __hip_atomic_load(p2, __ATOMIC_RELAXED, __HIP_MEMORY_SCOPE_AGENT);
            float vb = __hip_atomic_load(p2, __ATOMIC_RELAXED, __HIP_MEMORY_SCOPE_AGENT);
            float vc = __hip_atomic_load(p2, __ATOMIC_RELAXED, __HIP_MEMORY_SCOPE_AGENT);
            float vd = __hip_atomic_load(p2, __ATOMIC_RELAXED, __HIP_MEMORY_SCOPE_AGENT);
            int guard = 0;
            while (va < 1.0f && ++guard < 2000000) {   // failsafe: never hang
                va = vb; vb = vc; vc = vd;
                vd = __hip_atomic_load(p2, __ATOMIC_RELAXED, __HIP_MEMORY_SCOPE_AGENT);
            }
            so_nxt[tid] = va - 2.0f;
        }
        __syncthreads();                                   // B2: so_nxt sealed
    }

    // ======== final phase (proven structure, unchanged) ========
    // Barrier A among the 8 sibling blocks: everyone's t-loop done, all hs published.
    if (tid == 0) {
        __hip_atomic_fetch_add(&ctr[b * 32], 1u, __ATOMIC_RELAXED, __HIP_MEMORY_SCOPE_AGENT);
        int guard = 0;
        while (__hip_atomic_load(&ctr[b * 32], __ATOMIC_RELAXED, __HIP_MEMORY_SCOPE_AGENT) < 8u) {
            if (++guard > 2000000) break;
            __builtin_amdgcn_s_sleep(1);
        }
    }
    __syncthreads();

    // readout staging: load biased hs, subtract bias
    for (int idx = tid; idx < 16 * HH; idx += 512) {
        int tl = idx / HH, h = idx % HH;
        int t_g = sub * 16 + tl;
        s_hs[idx] = __hip_atomic_load(&hs[(t_g * BB + b) * HH + h],
                                      __ATOMIC_RELAXED, __HIP_MEMORY_SCOPE_AGENT) - 2.0f;
    }
    __syncthreads();
    {
        int t_loc = tid >> 5;          // 0..15
        int o     = tid & 31;
        int t_g   = sub * 16 + t_loc;
        const float* hp = &s_hs[t_loc * HH];
        float acc = bh2o[o];
#pragma unroll 4
        for (int h = 0; h < 257; ++h) {          // mask_o zero for h>256
            float m = (h == 256) ? -1.f : 1.f;   // h==256: sign -1, exist 1 (zc=63)
            acc = fmaf(fmaxf(Wh2o[o * HH + h], 0.f) * m, hp[h], acc);
        }
        float sg = frcp(1.f + fexp2(-acc * L2E));
        out[(t_g * BB + b) * OO + o] = sg;
    }

    // Barrier B: all siblings finished READING biased hs -> safe to rewrite
    __syncthreads();
    if (tid == 0) {
        __hip_atomic_fetch_add(&ctr[b * 32], 1u, __ATOMIC_RELAXED, __HIP_MEMORY_SCOPE_AGENT);
        int guard = 0;
        while (__hip_atomic_load(&ctr[b * 32], __ATOMIC_RELAXED, __HIP_MEMORY_SCOPE_AGENT) < 16u) {
            if (++guard > 2000000) break;
            __builtin_amdgcn_s_sleep(1);
        }
    }
    __syncthreads();

    // rewrite own rows of hs with TRUE values (word-granular agent stores)
    for (int idx = tid; idx < 40 * TT; idx += 512) {
        int row = idx >> 7;            // idx / 128
        int t   = idx & 127;
        __hip_atomic_store(&hs[(t * BB + b) * HH + h0 + row], s_hist[row * HPAD + t],
                           __ATOMIC_RELAXED, __HIP_MEMORY_SCOPE_AGENT);
    }
}

extern "C" void kernel_launch(void* const* d_in, const int* in_sizes, int n_in,
                              void* d_out, int out_size, void* d_ws, size_t ws_size,
                              hipStream_t stream) {
    const float* x     = (const float*)d_in[0];
    const float* Rs    = (const float*)d_in[1];
    const float* Wx2h  = (const float*)d_in[2];
    const float* Wh2h  = (const float*)d_in[3];
    const float* bh2h  = (const float*)d_in[4];
    const float* Wh2o  = (const float*)d_in[5];
    const float* bh2o  = (const float*)d_in[6];
    const float* Wattn = (const float*)d_in[7];
    const float* battn = (const float*)d_in[8];
    const float* cplas = (const float*)d_in[9];
    float* out = (float*)d_out;
    float* hs  = out + TT * BB * OO;
    unsigned* ctr = (unsigned*)d_ws;   // 32 counters, 128B apart

    hipMemsetAsync(d_ws, 0, 32 * 32 * sizeof(unsigned), stream);
    hipLaunchKernelGGL(leaky_rnn_kernel, dim3(256), dim3(512), 0, stream,
                       x, Rs, Wx2h, Wh2h, bh2h, Wh2o, bh2o, Wattn, battn, cplas,
                       out, hs, ctr);
}